// Round 3
// baseline (275.748 us; speedup 1.0000x reference)
//
#include <hip/hip_runtime.h>
#include <math.h>

#define N_NODES 100000
#define N_EDGES 3200000
#define IN_CH 256
#define NC 20        // combined output channels (10 mu + 10 logstd)
#define OC 10
#define NPB 128      // nodes per bucket (col >> 7)
#define NBUCK 782    // ceil(100000/128)
#define CAP 4864     // per-bucket capacity: mean 4096, sigma ~64 -> +12 sigma

// binning kernel geometry (R7): LDS counting sort, coalesced flush
#define CHUNK3 8192          // edges per block; 8192*6B stage + hists = 58.5KB LDS
#define NCHUNK3 391          // ceil(3.2M/8192); last chunk 5120 edges (div by 4)

// ---------- init per-bucket allocation cursors ----------
__global__ __launch_bounds__(256) void k_initptr(int* __restrict__ bptr) {
    int i = blockIdx.x * 256 + threadIdx.x;
    if (i < NBUCK) bptr[i] = i * CAP;
}

// ---------- LDS counting-sort binning: bucket-sorted staging, coalesced flush ----------
__global__ __launch_bounds__(1024) void k_bin3(const int* __restrict__ row,
                                               const int* __restrict__ col,
                                               int* __restrict__ bptr,
                                               int* __restrict__ bpairs) {
    __shared__ int   lh[NBUCK];      // counts -> scatter cursor
    __shared__ int   lscan[NBUCK];   // inclusive scan
    __shared__ int   gmino[NBUCK];   // gbase - lofs  (flush: dst = gmino[b] + j)
    __shared__ int   stage[CHUNK3];  // bucket-sorted packed pairs
    __shared__ unsigned short sbkt[CHUNK3];  // bucket id per staged slot

    int t = threadIdx.x;
    int e0 = blockIdx.x * CHUNK3;
    int nE = N_EDGES - e0; if (nE > CHUNK3) nE = CHUNK3;
    int n4 = nE >> 2;                 // chunk sizes divisible by 4
    const int4* c4 = (const int4*)(col + e0);
    const int4* r4 = (const int4*)(row + e0);

    for (int i = t; i < NBUCK; i += 1024) lh[i] = 0;
    __syncthreads();

    // phase 1: chunk histogram
    for (int j = t; j < n4; j += 1024) {
        int4 c = c4[j];
        atomicAdd(&lh[c.x >> 7], 1); atomicAdd(&lh[c.y >> 7], 1);
        atomicAdd(&lh[c.z >> 7], 1); atomicAdd(&lh[c.w >> 7], 1);
    }
    __syncthreads();

    // phase 2: inclusive scan over NBUCK (Hillis-Steele, 1024 threads cover 782)
    int cnt = 0;
    if (t < NBUCK) { cnt = lh[t]; lscan[t] = cnt; }
    __syncthreads();
    for (int o = 1; o < NBUCK; o <<= 1) {
        int add = 0;
        if (t < NBUCK && t >= o) add = lscan[t - o];
        __syncthreads();
        if (t < NBUCK) lscan[t] += add;
        __syncthreads();
    }
    // phase 3: reserve global space per bucket; set scatter cursors
    if (t < NBUCK) {
        int lofs = lscan[t] - cnt;
        int gbase = cnt ? atomicAdd(&bptr[t], cnt) : 0;
        gmino[t] = gbase - lofs;
        lh[t] = lofs;                 // scatter cursor starts at local offset
    }
    __syncthreads();

    // phase 4: scatter into LDS, bucket-sorted
    for (int j = t; j < n4; j += 1024) {
        int4 c = c4[j];
        int4 r = r4[j];
        int b0 = c.x >> 7, b1 = c.y >> 7, b2 = c.z >> 7, b3 = c.w >> 7;
        int s0 = atomicAdd(&lh[b0], 1);
        int s1 = atomicAdd(&lh[b1], 1);
        int s2 = atomicAdd(&lh[b2], 1);
        int s3 = atomicAdd(&lh[b3], 1);
        stage[s0] = (r.x << 7) | (c.x & 127); sbkt[s0] = (unsigned short)b0;
        stage[s1] = (r.y << 7) | (c.y & 127); sbkt[s1] = (unsigned short)b1;
        stage[s2] = (r.z << 7) | (c.z & 127); sbkt[s2] = (unsigned short)b2;
        stage[s3] = (r.w << 7) | (c.w & 127); sbkt[s3] = (unsigned short)b3;
    }
    __syncthreads();

    // phase 5: coalesced flush — consecutive lanes hit consecutive dst inside runs
    for (int j = t; j < nE; j += 1024) {
        int b = sbkt[j];
        int dst = gmino[b] + j;
        if (dst < (b + 1) * CAP) bpairs[dst] = stage[j];
    }
}

// ---------- per-node degree from bucket regions; dinv = rsqrt(deg+1) ----------
__global__ __launch_bounds__(256) void k_deg(const int* __restrict__ bptr,
                                             const int* __restrict__ bpairs,
                                             float* __restrict__ dinv) {
    __shared__ int lc[NPB];
    int b = blockIdx.x, t = threadIdx.x;
    if (t < NPB) lc[t] = 0;
    __syncthreads();
    int start = b * CAP;
    int n = bptr[b] - start; if (n > CAP) n = CAP;
    for (int p = t; p < n; p += 256)
        atomicAdd(&lc[bpairs[start + p] & 127], 1);
    __syncthreads();
    int node = b * NPB + t;
    if (t < NPB && node < N_NODES)
        dinv[node] = rsqrtf((float)(lc[t] + 1));   // +1 self loop
}

// ---------- bf16 pack helpers (RNE) ----------
__device__ __forceinline__ unsigned bfpack(float a, float b) {
    unsigned ua = __float_as_uint(a), ub = __float_as_uint(b);
    ua = (ua + 0x7FFFu + ((ua >> 16) & 1u)) >> 16;
    ub = (ub + 0x7FFFu + ((ub >> 16) & 1u)) >> 16;
    return ua | (ub << 16);
}
__device__ __forceinline__ float bflo(unsigned p) { return __uint_as_float(p << 16); }
__device__ __forceinline__ float bfhi(unsigned p) { return __uint_as_float(p & 0xFFFF0000u); }

// ---------- skinny GEMM, R9: thread-per-node, NO k-split, NO shuffles ----------
// R2 post-mortem: k-split reduction (ds_swizzle chains) + per-lane W reads were
// the DS-pipe cost. New mapping: thread = node; acc[20] private (no reduction);
// W reads are wave-UNIFORM -> LDS broadcast (conflict-free); x coalescing fixed
// by staging [256 node][32 k] panels through LDS (stride 36 = bank-spread).
__global__ __launch_bounds__(256) void k_gemm5(const float* __restrict__ x,
                                               const float* __restrict__ Wmu,
                                               const float* __restrict__ Wls,
                                               const float* __restrict__ dinv,
                                               unsigned* __restrict__ hbf) {
    __shared__ float sW[IN_CH * NC];     // 20480 B, [k][c] c-fastest
    __shared__ float sX[256 * 36];       // 36864 B, row stride 36 floats

    int t = threadIdx.x;
    int nbase = blockIdx.x * 256;

    for (int idx = t; idx < IN_CH * NC; idx += 256) {
        int k = idx / NC, c = idx - (idx / NC) * NC;
        sW[idx] = (c < OC) ? Wmu[k * OC + c] : Wls[k * OC + (c - OC)];
    }

    int node = nbase + t;

    float acc[NC];
#pragma unroll
    for (int c = 0; c < NC; c++) acc[c] = 0.0f;

    int trow = t >> 3;       // 0..31: row group for staging
    int tq   = t & 7;        // 0..7 : float4 slot within 32-float panel row

    for (int p = 0; p < 8; p++) {        // 8 k-panels of 32
        __syncthreads();                 // W ready (p=0) / prev compute done
        // stage x[nbase..nbase+255][p*32..p*32+31] -> sX, coalesced 128B runs
#pragma unroll
        for (int pass = 0; pass < 8; pass++) {
            int r = pass * 32 + trow;
            int gn = nbase + r; if (gn >= N_NODES) gn = N_NODES - 1;
            float4 v = *(const float4*)(x + (size_t)gn * IN_CH + p * 32 + tq * 4);
            *(float4*)&sX[r * 36 + tq * 4] = v;
        }
        __syncthreads();
        // compute this panel's 32 k
#pragma unroll
        for (int q = 0; q < 8; q++) {
            float4 xv = *(const float4*)&sX[t * 36 + q * 4];
            const float* wq = &sW[(p * 32 + q * 4) * NC];  // 4 k-rows x 20c, uniform
            float xj[4] = {xv.x, xv.y, xv.z, xv.w};
#pragma unroll
            for (int j = 0; j < 4; j++) {
#pragma unroll
                for (int c = 0; c < NC; c++)
                    acc[c] += xj[j] * wq[j * NC + c];
            }
        }
    }

    if (node < N_NODES) {
        float d = dinv[node];
        unsigned* hp = hbf + (size_t)node * 10;
        *(uint2*)(hp + 0) = make_uint2(bfpack(acc[0] * d,  acc[1] * d),
                                       bfpack(acc[2] * d,  acc[3] * d));
        *(uint2*)(hp + 2) = make_uint2(bfpack(acc[4] * d,  acc[5] * d),
                                       bfpack(acc[6] * d,  acc[7] * d));
        *(uint2*)(hp + 4) = make_uint2(bfpack(acc[8] * d,  acc[9] * d),
                                       bfpack(acc[10] * d, acc[11] * d));
        *(uint2*)(hp + 6) = make_uint2(bfpack(acc[12] * d, acc[13] * d),
                                       bfpack(acc[14] * d, acc[15] * d));
        *(uint2*)(hp + 8) = make_uint2(bfpack(acc[16] * d, acc[17] * d),
                                       bfpack(acc[18] * d, acc[19] * d));
    }
}

// ---------- fused sort+reduce per 128-node bucket ----------
__global__ __launch_bounds__(256) void k_agg4(const int* __restrict__ bptr,
                                              const int* __restrict__ bpairs,
                                              const unsigned* __restrict__ hbf,
                                              const float* __restrict__ bmu,
                                              const float* __restrict__ bls,
                                              float* __restrict__ out) {
    __shared__ int lcnt[NPB];    // hist -> cursor
    __shared__ int lscan[NPB];   // inclusive scan
    __shared__ int sCnt[NPB];    // per-node count
    __shared__ int ssrc[CAP];    // node-sorted src ids
    int b = blockIdx.x, t = threadIdx.x;
    int start = b * CAP;
    int n = bptr[b] - start; if (n > CAP) n = CAP;

    if (t < NPB) lcnt[t] = 0;
    __syncthreads();
    for (int p = t; p < n; p += 256)
        atomicAdd(&lcnt[bpairs[start + p] & 127], 1);
    __syncthreads();

    int cnt = 0;
    if (t < NPB) { cnt = lcnt[t]; lscan[t] = cnt; sCnt[t] = cnt; }
    __syncthreads();
    for (int o = 1; o < NPB; o <<= 1) {
        int add = 0;
        if (t < NPB && t >= o) add = lscan[t - o];
        __syncthreads();
        if (t < NPB) lscan[t] += add;
        __syncthreads();
    }
    if (t < NPB) lcnt[t] = lscan[t] - cnt;   // cursor = exclusive
    __syncthreads();

    for (int p = t; p < n; p += 256) {
        int pk = bpairs[start + p];
        int q = atomicAdd(&lcnt[pk & 127], 1);
        ssrc[q] = ((unsigned)pk) >> 7;
    }
    __syncthreads();

    // reduce: 2 threads per node, edge-split halves, shuffle combine
    int nl = t >> 1, half = t & 1;
    int node = b * NPB + nl;
    int ccnt = sCnt[nl];
    int base = lscan[nl] - ccnt;
    int mid = ccnt >> 1;
    int j0 = half ? mid : 0;
    int j1 = half ? ccnt : mid;

    float a[NC];
#pragma unroll
    for (int c = 0; c < NC; c++) a[c] = 0.0f;

#define ADDROW(R)                                                        \
    {                                                                    \
        const unsigned* hp_ = hbf + (size_t)(R) * 10;                    \
        uint2 q0 = *(const uint2*)(hp_ + 0);                             \
        uint2 q1 = *(const uint2*)(hp_ + 2);                             \
        uint2 q2 = *(const uint2*)(hp_ + 4);                             \
        uint2 q3 = *(const uint2*)(hp_ + 6);                             \
        uint2 q4 = *(const uint2*)(hp_ + 8);                             \
        a[0]  += bflo(q0.x); a[1]  += bfhi(q0.x);                        \
        a[2]  += bflo(q0.y); a[3]  += bfhi(q0.y);                        \
        a[4]  += bflo(q1.x); a[5]  += bfhi(q1.x);                        \
        a[6]  += bflo(q1.y); a[7]  += bfhi(q1.y);                        \
        a[8]  += bflo(q2.x); a[9]  += bfhi(q2.x);                        \
        a[10] += bflo(q2.y); a[11] += bfhi(q2.y);                        \
        a[12] += bflo(q3.x); a[13] += bfhi(q3.x);                        \
        a[14] += bflo(q3.y); a[15] += bfhi(q3.y);                        \
        a[16] += bflo(q4.x); a[17] += bfhi(q4.x);                        \
        a[18] += bflo(q4.y); a[19] += bfhi(q4.y);                        \
    }

    int j = j0;
    for (; j + 1 < j1; j += 2) {
        int r0 = ssrc[base + j];
        int r1 = ssrc[base + j + 1];
        ADDROW(r0);
        ADDROW(r1);
    }
    if (j < j1) {
        int r0 = ssrc[base + j];
        ADDROW(r0);
    }
    // self loop (h' already carries dinv[node]) on the even-half thread
    if (half == 0 && node < N_NODES) ADDROW(node);
#undef ADDROW

#pragma unroll
    for (int c = 0; c < NC; c++) a[c] += __shfl_xor(a[c], 1);

    if (half == 0 && node < N_NODES) {
        float dn = rsqrtf((float)(ccnt + 1));
        float* om = out + (size_t)node * OC;
        float* ol = out + (size_t)N_NODES * OC + (size_t)node * OC;
#pragma unroll
        for (int c = 0; c < OC; c++) {
            om[c] = dn * a[c]      + bmu[c];
            ol[c] = dn * a[c + OC] + bls[c];
        }
    }
}

// ======================= fallback (atomic scatter path, tiny ws) =======================
__global__ __launch_bounds__(256) void k_init_deg(float* __restrict__ deg) {
    int i = blockIdx.x * 256 + threadIdx.x;
    if (i < N_NODES) deg[i] = 1.0f;
}
__global__ __launch_bounds__(256) void k_count(const int* __restrict__ col, float* __restrict__ deg) {
    int e = blockIdx.x * 256 + threadIdx.x;
    if (e < N_EDGES) atomicAdd(&deg[col[e]], 1.0f);
}
__global__ __launch_bounds__(256) void k_dinvk(float* __restrict__ deg) {
    int i = blockIdx.x * 256 + threadIdx.x;
    if (i < N_NODES) deg[i] = rsqrtf(deg[i]);
}
__global__ __launch_bounds__(256) void k_gemm_f32(const float* __restrict__ x,
                                                  const float* __restrict__ Wmu,
                                                  const float* __restrict__ Wls,
                                                  float* __restrict__ h) {
    int node = blockIdx.x * 256 + threadIdx.x;
    if (node >= N_NODES) return;
    const float4* x4 = (const float4*)(x + (size_t)node * IN_CH);
    float acc[NC];
#pragma unroll
    for (int c = 0; c < NC; c++) acc[c] = 0.0f;
    for (int k4 = 0; k4 < IN_CH / 4; k4++) {
        float4 xv = x4[k4];
        float xk[4] = {xv.x, xv.y, xv.z, xv.w};
#pragma unroll
        for (int kk = 0; kk < 4; kk++) {
            const float* wm = Wmu + (k4 * 4 + kk) * OC;
            const float* wl = Wls + (k4 * 4 + kk) * OC;
#pragma unroll
            for (int c = 0; c < OC; c++) {
                acc[c]      += xk[kk] * wm[c];
                acc[c + OC] += xk[kk] * wl[c];
            }
        }
    }
    float* hp = h + (size_t)node * NC;
#pragma unroll
    for (int c = 0; c < NC; c++) hp[c] = acc[c];
}
__global__ __launch_bounds__(256) void k_scatter(const int* __restrict__ row, const int* __restrict__ col,
                                                 const float* __restrict__ dinv, const float* __restrict__ h,
                                                 float* __restrict__ out) {
    int e = blockIdx.x * 256 + threadIdx.x;
    if (e >= N_EDGES) return;
    int r = row[e], c = col[e];
    float s = dinv[r] * dinv[c];
    const float* hp = h + (size_t)r * NC;
    float* om = out + (size_t)c * OC;
    float* ol = om + (size_t)N_NODES * OC;
#pragma unroll
    for (int k = 0; k < OC; k++) atomicAdd(om + k, hp[k] * s);
#pragma unroll
    for (int k = 0; k < OC; k++) atomicAdd(ol + k, hp[OC + k] * s);
}
__global__ __launch_bounds__(256) void k_final(const float* __restrict__ h, const float* __restrict__ dinv,
                                               const float* __restrict__ bmu, const float* __restrict__ bls,
                                               float* __restrict__ out) {
    int i = blockIdx.x * 256 + threadIdx.x;
    if (i >= N_NODES * OC) return;
    int node = i / OC, c = i - node * OC;
    float d = dinv[node];
    float d2 = d * d;
    out[i]                += h[node * NC + c]      * d2 + bmu[c];
    out[N_NODES * OC + i] += h[node * NC + OC + c] * d2 + bls[c];
}

extern "C" void kernel_launch(void* const* d_in, const int* in_sizes, int n_in,
                              void* d_out, int out_size, void* d_ws, size_t ws_size,
                              hipStream_t stream) {
    const float* x   = (const float*)d_in[0];
    const int*   ei  = (const int*)d_in[1];
    const float* Wmu = (const float*)d_in[2];
    const float* bmu = (const float*)d_in[3];
    const float* Wls = (const float*)d_in[4];
    const float* bls = (const float*)d_in[5];
    float* out = (float*)d_out;

    const int* row = ei;            // edge_index[0] (sources)
    const int* col = ei + N_EDGES;  // edge_index[1] (targets)

    // ws layout:
    //   bptr   int[NBUCK]      @ 0       (3.1 KB)
    //   dinv   f32[100096]     @ 8 KB    (400 KB)
    //   hbf    u32[100000*10]  @ 512 KB  (4 MB, bf16-packed dinv-prescaled h)
    //   bpairs int[NBUCK*CAP]  @ 4.5 MB  (15.2 MB; packed (row<<7)|(col&127))
    const size_t BPAIRS_OFF = (size_t)(9 << 19);   // 4.5 MiB
    const size_t REQ = BPAIRS_OFF + (size_t)NBUCK * CAP * 4;

    if (ws_size >= REQ) {
        char* w = (char*)d_ws;
        int*      bptr   = (int*)(w);
        float*    dinv   = (float*)(w + 8192);
        unsigned* hbf    = (unsigned*)(w + (512 << 10));
        int*      bpairs = (int*)(w + BPAIRS_OFF);

        k_initptr<<<(NBUCK + 255) / 256, 256, 0, stream>>>(bptr);
        k_bin3<<<NCHUNK3, 1024, 0, stream>>>(row, col, bptr, bpairs);
        k_deg<<<NBUCK, 256, 0, stream>>>(bptr, bpairs, dinv);
        k_gemm5<<<(N_NODES + 255) / 256, 256, 0, stream>>>(x, Wmu, Wls, dinv, hbf);
        k_agg4<<<NBUCK, 256, 0, stream>>>(bptr, bpairs, hbf, bmu, bls, out);
    } else {
        float* deg = (float*)d_ws;
        float* h   = (float*)((char*)d_ws + (1 << 20));
        hipMemsetAsync(d_out, 0, (size_t)out_size * sizeof(float), stream);
        k_init_deg<<<(N_NODES + 255) / 256, 256, 0, stream>>>(deg);
        k_count<<<(N_EDGES + 255) / 256, 256, 0, stream>>>(col, deg);
        k_dinvk<<<(N_NODES + 255) / 256, 256, 0, stream>>>(deg);
        k_gemm_f32<<<(N_NODES + 255) / 256, 256, 0, stream>>>(x, Wmu, Wls, h);
        k_scatter<<<(N_EDGES + 255) / 256, 256, 0, stream>>>(row, col, deg, h, out);
        k_final<<<(N_NODES * OC + 255) / 256, 256, 0, stream>>>(h, deg, bmu, bls, out);
    }
}

// Round 4
// 262.076 us; speedup vs baseline: 1.0522x; 1.0522x over previous
//
#include <hip/hip_runtime.h>
#include <math.h>

#define N_NODES 100000
#define N_EDGES 3200000
#define IN_CH 256
#define NC 20        // combined output channels (10 mu + 10 logstd)
#define OC 10
#define NPB 128      // nodes per bucket (col >> 7)
#define NBUCK 782    // ceil(100000/128)
#define CAP 4864     // per-bucket capacity: mean 4096, sigma ~64 -> +12 sigma

// binning kernel geometry (R7): LDS counting sort, coalesced flush
#define CHUNK3 8192          // edges per block; 8192*6B stage + hists = 58.5KB LDS
#define NCHUNK3 391          // ceil(3.2M/8192); last chunk 5120 edges (div by 4)

// ---------- init per-bucket allocation cursors ----------
__global__ __launch_bounds__(256) void k_initptr(int* __restrict__ bptr) {
    int i = blockIdx.x * 256 + threadIdx.x;
    if (i < NBUCK) bptr[i] = i * CAP;
}

// ---------- LDS counting-sort binning: bucket-sorted staging, coalesced flush ----------
__global__ __launch_bounds__(1024) void k_bin3(const int* __restrict__ row,
                                               const int* __restrict__ col,
                                               int* __restrict__ bptr,
                                               int* __restrict__ bpairs) {
    __shared__ int   lh[NBUCK];      // counts -> scatter cursor
    __shared__ int   lscan[NBUCK];   // inclusive scan
    __shared__ int   gmino[NBUCK];   // gbase - lofs  (flush: dst = gmino[b] + j)
    __shared__ int   stage[CHUNK3];  // bucket-sorted packed pairs
    __shared__ unsigned short sbkt[CHUNK3];  // bucket id per staged slot

    int t = threadIdx.x;
    int e0 = blockIdx.x * CHUNK3;
    int nE = N_EDGES - e0; if (nE > CHUNK3) nE = CHUNK3;
    int n4 = nE >> 2;                 // chunk sizes divisible by 4
    const int4* c4 = (const int4*)(col + e0);
    const int4* r4 = (const int4*)(row + e0);

    for (int i = t; i < NBUCK; i += 1024) lh[i] = 0;
    __syncthreads();

    // phase 1: chunk histogram
    for (int j = t; j < n4; j += 1024) {
        int4 c = c4[j];
        atomicAdd(&lh[c.x >> 7], 1); atomicAdd(&lh[c.y >> 7], 1);
        atomicAdd(&lh[c.z >> 7], 1); atomicAdd(&lh[c.w >> 7], 1);
    }
    __syncthreads();

    // phase 2: inclusive scan over NBUCK (Hillis-Steele, 1024 threads cover 782)
    int cnt = 0;
    if (t < NBUCK) { cnt = lh[t]; lscan[t] = cnt; }
    __syncthreads();
    for (int o = 1; o < NBUCK; o <<= 1) {
        int add = 0;
        if (t < NBUCK && t >= o) add = lscan[t - o];
        __syncthreads();
        if (t < NBUCK) lscan[t] += add;
        __syncthreads();
    }
    // phase 3: reserve global space per bucket; set scatter cursors
    if (t < NBUCK) {
        int lofs = lscan[t] - cnt;
        int gbase = cnt ? atomicAdd(&bptr[t], cnt) : 0;
        gmino[t] = gbase - lofs;
        lh[t] = lofs;                 // scatter cursor starts at local offset
    }
    __syncthreads();

    // phase 4: scatter into LDS, bucket-sorted
    for (int j = t; j < n4; j += 1024) {
        int4 c = c4[j];
        int4 r = r4[j];
        int b0 = c.x >> 7, b1 = c.y >> 7, b2 = c.z >> 7, b3 = c.w >> 7;
        int s0 = atomicAdd(&lh[b0], 1);
        int s1 = atomicAdd(&lh[b1], 1);
        int s2 = atomicAdd(&lh[b2], 1);
        int s3 = atomicAdd(&lh[b3], 1);
        stage[s0] = (r.x << 7) | (c.x & 127); sbkt[s0] = (unsigned short)b0;
        stage[s1] = (r.y << 7) | (c.y & 127); sbkt[s1] = (unsigned short)b1;
        stage[s2] = (r.z << 7) | (c.z & 127); sbkt[s2] = (unsigned short)b2;
        stage[s3] = (r.w << 7) | (c.w & 127); sbkt[s3] = (unsigned short)b3;
    }
    __syncthreads();

    // phase 5: coalesced flush — consecutive lanes hit consecutive dst inside runs
    for (int j = t; j < nE; j += 1024) {
        int b = sbkt[j];
        int dst = gmino[b] + j;
        if (dst < (b + 1) * CAP) bpairs[dst] = stage[j];
    }
}

// ---------- per-node degree from bucket regions; dinv = rsqrt(deg+1) ----------
__global__ __launch_bounds__(256) void k_deg(const int* __restrict__ bptr,
                                             const int* __restrict__ bpairs,
                                             float* __restrict__ dinv) {
    __shared__ int lc[NPB];
    int b = blockIdx.x, t = threadIdx.x;
    if (t < NPB) lc[t] = 0;
    __syncthreads();
    int start = b * CAP;
    int n = bptr[b] - start; if (n > CAP) n = CAP;
    for (int p = t; p < n; p += 256)
        atomicAdd(&lc[bpairs[start + p] & 127], 1);
    __syncthreads();
    int node = b * NPB + t;
    if (t < NPB && node < N_NODES)
        dinv[node] = rsqrtf((float)(lc[t] + 1));   // +1 self loop
}

// ---------- bf16 pack helpers (RNE) ----------
__device__ __forceinline__ unsigned bfpack(float a, float b) {
    unsigned ua = __float_as_uint(a), ub = __float_as_uint(b);
    ua = (ua + 0x7FFFu + ((ua >> 16) & 1u)) >> 16;
    ub = (ub + 0x7FFFu + ((ub >> 16) & 1u)) >> 16;
    return ua | (ub << 16);
}
__device__ __forceinline__ float bflo(unsigned p) { return __uint_as_float(p << 16); }
__device__ __forceinline__ float bfhi(unsigned p) { return __uint_as_float(p & 0xFFFF0000u); }

// ---------- skinny GEMM, R10: gemm3 structure, G=2 nodes/thread, 782 blocks ----------
// gemm3 (G=4, 391 blocks, 66.5us) was grid-starved at 1.5 blocks/CU / 13.6% occ.
// Same proven structure, G=2: grid 782 -> 3 blocks/CU, ~12 waves/CU, acc 40 VGPR.
__global__ __launch_bounds__(256) void k_gemm6(const float* __restrict__ x,
                                               const float* __restrict__ Wmu,
                                               const float* __restrict__ Wls,
                                               const float* __restrict__ dinv,
                                               unsigned* __restrict__ hbf) {
    __shared__ float sW[NC * 272];
    int t = threadIdx.x;
    for (int idx = t; idx < IN_CH * OC; idx += 256) {
        int k = idx / OC, c = idx - (idx / OC) * OC;
        int kk = k >> 6, j = k & 63;
        sW[c * 272 + kk * 68 + j]          = Wmu[idx];
        sW[(c + OC) * 272 + kk * 68 + j]   = Wls[idx];
    }
    __syncthreads();

    int kk = t & 3;
    int slot = t >> 2;                       // 0..63
    int n0 = blockIdx.x * 128 + slot;        // thread's nodes: n0, n0+64

    int nd[2];
#pragma unroll
    for (int u = 0; u < 2; u++) {
        int n = n0 + u * 64;
        nd[u] = (n < N_NODES) ? n : (N_NODES - 1);   // clamp for safe loads
    }

    float acc[2][NC];
#pragma unroll
    for (int u = 0; u < 2; u++)
#pragma unroll
        for (int c = 0; c < NC; c++) acc[u][c] = 0.0f;

    const float4* x4 = (const float4*)x;

#pragma unroll 4
    for (int j4 = 0; j4 < 16; j4++) {
        float4 xv0 = x4[(size_t)nd[0] * 64 + kk * 16 + j4];
        float4 xv1 = x4[(size_t)nd[1] * 64 + kk * 16 + j4];
#pragma unroll
        for (int c = 0; c < NC; c++) {
            float4 w = *(const float4*)&sW[c * 272 + kk * 68 + j4 * 4];
            acc[0][c] += xv0.x * w.x + xv0.y * w.y + xv0.z * w.z + xv0.w * w.w;
            acc[1][c] += xv1.x * w.x + xv1.y * w.y + xv1.z * w.z + xv1.w * w.w;
        }
    }

    // quad reduction (lanes node*4+kk, quads lane-aligned)
#pragma unroll
    for (int u = 0; u < 2; u++)
#pragma unroll
        for (int c = 0; c < NC; c++) {
            acc[u][c] += __shfl_xor(acc[u][c], 2);
            acc[u][c] += __shfl_xor(acc[u][c], 1);
        }

    if (kk == 0) {
#pragma unroll
        for (int u = 0; u < 2; u++) {
            int n = n0 + u * 64;
            if (n >= N_NODES) continue;
            float d = dinv[n];
            unsigned* hp = hbf + (size_t)n * 10;
            *(uint2*)(hp + 0) = make_uint2(bfpack(acc[u][0] * d,  acc[u][1] * d),
                                           bfpack(acc[u][2] * d,  acc[u][3] * d));
            *(uint2*)(hp + 2) = make_uint2(bfpack(acc[u][4] * d,  acc[u][5] * d),
                                           bfpack(acc[u][6] * d,  acc[u][7] * d));
            *(uint2*)(hp + 4) = make_uint2(bfpack(acc[u][8] * d,  acc[u][9] * d),
                                           bfpack(acc[u][10] * d, acc[u][11] * d));
            *(uint2*)(hp + 6) = make_uint2(bfpack(acc[u][12] * d, acc[u][13] * d),
                                           bfpack(acc[u][14] * d, acc[u][15] * d));
            *(uint2*)(hp + 8) = make_uint2(bfpack(acc[u][16] * d, acc[u][17] * d),
                                           bfpack(acc[u][18] * d, acc[u][19] * d));
        }
    }
}

// ---------- fused sort+reduce per 128-node bucket ----------
__global__ __launch_bounds__(256) void k_agg4(const int* __restrict__ bptr,
                                              const int* __restrict__ bpairs,
                                              const unsigned* __restrict__ hbf,
                                              const float* __restrict__ bmu,
                                              const float* __restrict__ bls,
                                              float* __restrict__ out) {
    __shared__ int lcnt[NPB];    // hist -> cursor
    __shared__ int lscan[NPB];   // inclusive scan
    __shared__ int sCnt[NPB];    // per-node count
    __shared__ int ssrc[CAP];    // node-sorted src ids
    int b = blockIdx.x, t = threadIdx.x;
    int start = b * CAP;
    int n = bptr[b] - start; if (n > CAP) n = CAP;

    if (t < NPB) lcnt[t] = 0;
    __syncthreads();
    for (int p = t; p < n; p += 256)
        atomicAdd(&lcnt[bpairs[start + p] & 127], 1);
    __syncthreads();

    int cnt = 0;
    if (t < NPB) { cnt = lcnt[t]; lscan[t] = cnt; sCnt[t] = cnt; }
    __syncthreads();
    for (int o = 1; o < NPB; o <<= 1) {
        int add = 0;
        if (t < NPB && t >= o) add = lscan[t - o];
        __syncthreads();
        if (t < NPB) lscan[t] += add;
        __syncthreads();
    }
    if (t < NPB) lcnt[t] = lscan[t] - cnt;   // cursor = exclusive
    __syncthreads();

    for (int p = t; p < n; p += 256) {
        int pk = bpairs[start + p];
        int q = atomicAdd(&lcnt[pk & 127], 1);
        ssrc[q] = ((unsigned)pk) >> 7;
    }
    __syncthreads();

    // reduce: 2 threads per node, edge-split halves, shuffle combine
    int nl = t >> 1, half = t & 1;
    int node = b * NPB + nl;
    int ccnt = sCnt[nl];
    int base = lscan[nl] - ccnt;
    int mid = ccnt >> 1;
    int j0 = half ? mid : 0;
    int j1 = half ? ccnt : mid;

    float a[NC];
#pragma unroll
    for (int c = 0; c < NC; c++) a[c] = 0.0f;

#define ADDROW(R)                                                        \
    {                                                                    \
        const unsigned* hp_ = hbf + (size_t)(R) * 10;                    \
        uint2 q0 = *(const uint2*)(hp_ + 0);                             \
        uint2 q1 = *(const uint2*)(hp_ + 2);                             \
        uint2 q2 = *(const uint2*)(hp_ + 4);                             \
        uint2 q3 = *(const uint2*)(hp_ + 6);                             \
        uint2 q4 = *(const uint2*)(hp_ + 8);                             \
        a[0]  += bflo(q0.x); a[1]  += bfhi(q0.x);                        \
        a[2]  += bflo(q0.y); a[3]  += bfhi(q0.y);                        \
        a[4]  += bflo(q1.x); a[5]  += bfhi(q1.x);                        \
        a[6]  += bflo(q1.y); a[7]  += bfhi(q1.y);                        \
        a[8]  += bflo(q2.x); a[9]  += bfhi(q2.x);                        \
        a[10] += bflo(q2.y); a[11] += bfhi(q2.y);                        \
        a[12] += bflo(q3.x); a[13] += bfhi(q3.x);                        \
        a[14] += bflo(q3.y); a[15] += bfhi(q3.y);                        \
        a[16] += bflo(q4.x); a[17] += bfhi(q4.x);                        \
        a[18] += bflo(q4.y); a[19] += bfhi(q4.y);                        \
    }

    int j = j0;
    for (; j + 1 < j1; j += 2) {
        int r0 = ssrc[base + j];
        int r1 = ssrc[base + j + 1];
        ADDROW(r0);
        ADDROW(r1);
    }
    if (j < j1) {
        int r0 = ssrc[base + j];
        ADDROW(r0);
    }
    // self loop (h' already carries dinv[node]) on the even-half thread
    if (half == 0 && node < N_NODES) ADDROW(node);
#undef ADDROW

#pragma unroll
    for (int c = 0; c < NC; c++) a[c] += __shfl_xor(a[c], 1);

    if (half == 0 && node < N_NODES) {
        float dn = rsqrtf((float)(ccnt + 1));
        float* om = out + (size_t)node * OC;
        float* ol = out + (size_t)N_NODES * OC + (size_t)node * OC;
#pragma unroll
        for (int c = 0; c < OC; c++) {
            om[c] = dn * a[c]      + bmu[c];
            ol[c] = dn * a[c + OC] + bls[c];
        }
    }
}

// ======================= fallback (atomic scatter path, tiny ws) =======================
__global__ __launch_bounds__(256) void k_init_deg(float* __restrict__ deg) {
    int i = blockIdx.x * 256 + threadIdx.x;
    if (i < N_NODES) deg[i] = 1.0f;
}
__global__ __launch_bounds__(256) void k_count(const int* __restrict__ col, float* __restrict__ deg) {
    int e = blockIdx.x * 256 + threadIdx.x;
    if (e < N_EDGES) atomicAdd(&deg[col[e]], 1.0f);
}
__global__ __launch_bounds__(256) void k_dinvk(float* __restrict__ deg) {
    int i = blockIdx.x * 256 + threadIdx.x;
    if (i < N_NODES) deg[i] = rsqrtf(deg[i]);
}
__global__ __launch_bounds__(256) void k_gemm_f32(const float* __restrict__ x,
                                                  const float* __restrict__ Wmu,
                                                  const float* __restrict__ Wls,
                                                  float* __restrict__ h) {
    int node = blockIdx.x * 256 + threadIdx.x;
    if (node >= N_NODES) return;
    const float4* x4 = (const float4*)(x + (size_t)node * IN_CH);
    float acc[NC];
#pragma unroll
    for (int c = 0; c < NC; c++) acc[c] = 0.0f;
    for (int k4 = 0; k4 < IN_CH / 4; k4++) {
        float4 xv = x4[k4];
        float xk[4] = {xv.x, xv.y, xv.z, xv.w};
#pragma unroll
        for (int kk = 0; kk < 4; kk++) {
            const float* wm = Wmu + (k4 * 4 + kk) * OC;
            const float* wl = Wls + (k4 * 4 + kk) * OC;
#pragma unroll
            for (int c = 0; c < OC; c++) {
                acc[c]      += xk[kk] * wm[c];
                acc[c + OC] += xk[kk] * wl[c];
            }
        }
    }
    float* hp = h + (size_t)node * NC;
#pragma unroll
    for (int c = 0; c < NC; c++) hp[c] = acc[c];
}
__global__ __launch_bounds__(256) void k_scatter(const int* __restrict__ row, const int* __restrict__ col,
                                                 const float* __restrict__ dinv, const float* __restrict__ h,
                                                 float* __restrict__ out) {
    int e = blockIdx.x * 256 + threadIdx.x;
    if (e >= N_EDGES) return;
    int r = row[e], c = col[e];
    float s = dinv[r] * dinv[c];
    const float* hp = h + (size_t)r * NC;
    float* om = out + (size_t)c * OC;
    float* ol = om + (size_t)N_NODES * OC;
#pragma unroll
    for (int k = 0; k < OC; k++) atomicAdd(om + k, hp[k] * s);
#pragma unroll
    for (int k = 0; k < OC; k++) atomicAdd(ol + k, hp[OC + k] * s);
}
__global__ __launch_bounds__(256) void k_final(const float* __restrict__ h, const float* __restrict__ dinv,
                                               const float* __restrict__ bmu, const float* __restrict__ bls,
                                               float* __restrict__ out) {
    int i = blockIdx.x * 256 + threadIdx.x;
    if (i >= N_NODES * OC) return;
    int node = i / OC, c = i - node * OC;
    float d = dinv[node];
    float d2 = d * d;
    out[i]                += h[node * NC + c]      * d2 + bmu[c];
    out[N_NODES * OC + i] += h[node * NC + OC + c] * d2 + bls[c];
}

extern "C" void kernel_launch(void* const* d_in, const int* in_sizes, int n_in,
                              void* d_out, int out_size, void* d_ws, size_t ws_size,
                              hipStream_t stream) {
    const float* x   = (const float*)d_in[0];
    const int*   ei  = (const int*)d_in[1];
    const float* Wmu = (const float*)d_in[2];
    const float* bmu = (const float*)d_in[3];
    const float* Wls = (const float*)d_in[4];
    const float* bls = (const float*)d_in[5];
    float* out = (float*)d_out;

    const int* row = ei;            // edge_index[0] (sources)
    const int* col = ei + N_EDGES;  // edge_index[1] (targets)

    // ws layout:
    //   bptr   int[NBUCK]      @ 0       (3.1 KB)
    //   dinv   f32[100096]     @ 8 KB    (400 KB)
    //   hbf    u32[100000*10]  @ 512 KB  (4 MB, bf16-packed dinv-prescaled h)
    //   bpairs int[NBUCK*CAP]  @ 4.5 MB  (15.2 MB; packed (row<<7)|(col&127))
    const size_t BPAIRS_OFF = (size_t)(9 << 19);   // 4.5 MiB
    const size_t REQ = BPAIRS_OFF + (size_t)NBUCK * CAP * 4;

    if (ws_size >= REQ) {
        char* w = (char*)d_ws;
        int*      bptr   = (int*)(w);
        float*    dinv   = (float*)(w + 8192);
        unsigned* hbf    = (unsigned*)(w + (512 << 10));
        int*      bpairs = (int*)(w + BPAIRS_OFF);

        k_initptr<<<(NBUCK + 255) / 256, 256, 0, stream>>>(bptr);
        k_bin3<<<NCHUNK3, 1024, 0, stream>>>(row, col, bptr, bpairs);
        k_deg<<<NBUCK, 256, 0, stream>>>(bptr, bpairs, dinv);
        k_gemm6<<<(N_NODES + 127) / 128, 256, 0, stream>>>(x, Wmu, Wls, dinv, hbf);
        k_agg4<<<NBUCK, 256, 0, stream>>>(bptr, bpairs, hbf, bmu, bls, out);
    } else {
        float* deg = (float*)d_ws;
        float* h   = (float*)((char*)d_ws + (1 << 20));
        hipMemsetAsync(d_out, 0, (size_t)out_size * sizeof(float), stream);
        k_init_deg<<<(N_NODES + 255) / 256, 256, 0, stream>>>(deg);
        k_count<<<(N_EDGES + 255) / 256, 256, 0, stream>>>(col, deg);
        k_dinvk<<<(N_NODES + 255) / 256, 256, 0, stream>>>(deg);
        k_gemm_f32<<<(N_NODES + 255) / 256, 256, 0, stream>>>(x, Wmu, Wls, h);
        k_scatter<<<(N_EDGES + 255) / 256, 256, 0, stream>>>(row, col, deg, h, out);
        k_final<<<(N_NODES * OC + 255) / 256, 256, 0, stream>>>(h, deg, bmu, bls, out);
    }
}